// Round 2
// baseline (416.006 us; speedup 1.0000x reference)
//
#include <hip/hip_runtime.h>

// emb[b,n,i] = cos(pi * i * x[b,n]),  i = 0..127
// rows = b*n = 1,048,576 ; out row-major [rows][128] f32 (512 MiB -> write-bound).
//
// cos(pi*i*x) = cos(2*pi*(i*x/2)); v_cos_f32 takes REVOLUTIONS, so
// val = v_cos(fract(x/2 * i)) -- fract is an exact period reduction.
//
// Structure (round 2): exact grid, no grid-stride loop, 64 B/thread via four
// independent dwordx4 nontemporal stores (output > L3, never re-read).
// 8 threads per row; each thread owns 16 consecutive i of one row.

typedef float f32x4 __attribute__((ext_vector_type(4)));

__global__ __launch_bounds__(256) void Emb_37967510896970_kernel(
    const float* __restrict__ x, f32x4* __restrict__ out, long long total_elems)
{
    const long long tid = (long long)blockIdx.x * 256 + threadIdx.x;
    if (tid * 16 >= total_elems) return;

    const int row = (int)(tid >> 3);          // 8 threads cover one 128-wide row
    const int sub = (int)tid & 7;             // which 16-element slice
    const float h  = 0.5f * x[row];           // revolutions per unit i
    const float hb = h * (float)(sub << 4);   // h * i0

    f32x4 v[4];
#pragma unroll
    for (int q = 0; q < 4; ++q) {
#pragma unroll
        for (int k = 0; k < 4; ++k) {
            // angle in revolutions: h*(i0 + 4q + k) = fma(h, const, hb)
            float ang = fmaf(h, (float)(4 * q + k), hb);
            v[q][k] = __builtin_amdgcn_cosf(__builtin_amdgcn_fractf(ang));
        }
    }

    f32x4* p = out + tid * 4;
#pragma unroll
    for (int q = 0; q < 4; ++q)
        __builtin_nontemporal_store(v[q], p + q);
}

extern "C" void kernel_launch(void* const* d_in, const int* in_sizes, int n_in,
                              void* d_out, int out_size, void* d_ws, size_t ws_size,
                              hipStream_t stream) {
    const float* x = (const float*)d_in[0];
    f32x4* out = (f32x4*)d_out;
    const long long total_elems = (long long)out_size;     // rows * 128
    const long long threads = (total_elems + 15) / 16;     // 16 elems / thread
    const int grid = (int)((threads + 255) / 256);         // exact grid, no loop
    Emb_37967510896970_kernel<<<grid, 256, 0, stream>>>(x, out, total_elems);
}

// Round 3
// 104.686 us; speedup vs baseline: 3.9738x; 3.9738x over previous
//
#include <hip/hip_runtime.h>

// emb[b,n,i] = cos(pi * i * x[b,n]),  i = 0..127
// rows = b*n = 1,048,576 ; out row-major [rows][128] f32 (512 MiB -> write-bound).
//
// cos(pi*i*x) = cos(2*pi*(i*x/2)); v_cos_f32 takes REVOLUTIONS, so
// val = v_cos(fract(x/2 * i)) -- fract is an exact period reduction.
//
// Round-3 structure: exact grid, no loop. Block = 256 threads covers 32 rows
// (1024 float4). Thread issues 4 stores; store q writes float4 index
//   f = blockIdx*1024 + q*256 + threadIdx
// so each wave store is a full contiguous 1 KiB line (round-2 lesson:
// per-lane-contiguous or WRITE_SIZE doubles). Plain stores (no nt): L2
// merges and drains; fill kernel reaches 6.8 TB/s this way.

typedef float f32x4 __attribute__((ext_vector_type(4)));

__global__ __launch_bounds__(256) void Emb_37967510896970_kernel(
    const float* __restrict__ x, f32x4* __restrict__ out, int total_rows)
{
    const int tid  = threadIdx.x;
    const int ty   = tid >> 5;           // 0..7: row group within block
    const int slot = tid & 31;           // float4 slot within row
    const int row0 = blockIdx.x * 32 + ty;   // thread's rows: row0 + 8q

    // independent up-front loads (x is 4 MiB -> L3-resident broadcast reads)
    float h[4];
#pragma unroll
    for (int q = 0; q < 4; ++q) {
        int r = row0 + 8 * q;
        h[q] = 0.5f * x[r < total_rows ? r : 0];
    }

    const float i0 = (float)(slot << 2);

    f32x4 v[4];
#pragma unroll
    for (int q = 0; q < 4; ++q) {
        const float hb = h[q] * i0;
#pragma unroll
        for (int k = 0; k < 4; ++k) {
            float ang = fmaf(h[q], (float)k, hb);   // h*(i0+k) revolutions
            v[q][k] = __builtin_amdgcn_cosf(__builtin_amdgcn_fractf(ang));
        }
    }

    f32x4* p = out + (size_t)blockIdx.x * 1024 + tid;
#pragma unroll
    for (int q = 0; q < 4; ++q) {
        int r = row0 + 8 * q;
        if (r < total_rows) p[q * 256] = v[q];
    }
}

extern "C" void kernel_launch(void* const* d_in, const int* in_sizes, int n_in,
                              void* d_out, int out_size, void* d_ws, size_t ws_size,
                              hipStream_t stream) {
    const float* x = (const float*)d_in[0];
    f32x4* out = (f32x4*)d_out;
    const int total_rows = in_sizes[0];              // 1,048,576
    const int grid = (total_rows + 31) / 32;         // 32 rows per block, exact
    Emb_37967510896970_kernel<<<grid, 256, 0, stream>>>(x, out, total_rows);
}

// Round 4
// 103.956 us; speedup vs baseline: 4.0017x; 1.0070x over previous
//
#include <hip/hip_runtime.h>

// emb[b,n,i] = cos(pi * i * x[b,n]),  i = 0..127
// rows = b*n = 1,048,576 ; out row-major [rows][128] f32 (512 MiB -> write-bound).
//
// cos(pi*i*x) = cos(2*pi*(i*x/2)); v_cos_f32 takes REVOLUTIONS, so
// val = v_cos(fract(x/2 * i)) -- fract is an exact period reduction.
//
// Round-4: same coalesced mapping as round 3 (each wave store = contiguous
// 1 KiB; round-2 lesson: anything else doubles WRITE_SIZE), but 2x work per
// thread (8 float4 = 128 B) to halve wave count and amortize the per-wave
// kernarg-load/setup prologue. Full-line nontemporal stores: output is a
// 512 MiB stream never re-read -- skip L2 write-allocate churn.

typedef float f32x4 __attribute__((ext_vector_type(4)));

__global__ __launch_bounds__(256) void Emb_37967510896970_kernel(
    const float* __restrict__ x, f32x4* __restrict__ out, int total_rows)
{
    const int tid  = threadIdx.x;
    const int ty   = tid >> 5;               // 0..7: row group within block
    const int slot = tid & 31;               // float4 slot within row
    const int row0 = blockIdx.x * 64 + ty;   // thread's rows: row0 + 8q, q=0..7

    // independent up-front loads (x is 4 MiB, broadcast within wave, L2/L3-hit)
    float h[8];
#pragma unroll
    for (int q = 0; q < 8; ++q) {
        int r = row0 + 8 * q;
        h[q] = 0.5f * x[r < total_rows ? r : 0];
    }

    const float i0 = (float)(slot << 2);

    f32x4 v[8];
#pragma unroll
    for (int q = 0; q < 8; ++q) {
        const float hb = h[q] * i0;
#pragma unroll
        for (int k = 0; k < 4; ++k) {
            float ang = fmaf(h[q], (float)k, hb);   // h*(i0+k) revolutions
            v[q][k] = __builtin_amdgcn_cosf(__builtin_amdgcn_fractf(ang));
        }
    }

    // store q -> float4 index blockIdx*2048 + q*256 + tid : wave-contiguous 1 KiB
    f32x4* p = out + (size_t)blockIdx.x * 2048 + tid;
#pragma unroll
    for (int q = 0; q < 8; ++q) {
        int r = row0 + 8 * q;
        if (r < total_rows) __builtin_nontemporal_store(v[q], p + q * 256);
    }
}

extern "C" void kernel_launch(void* const* d_in, const int* in_sizes, int n_in,
                              void* d_out, int out_size, void* d_ws, size_t ws_size,
                              hipStream_t stream) {
    const float* x = (const float*)d_in[0];
    f32x4* out = (f32x4*)d_out;
    const int total_rows = in_sizes[0];              // 1,048,576
    const int grid = (total_rows + 63) / 64;         // 64 rows per block, exact
    Emb_37967510896970_kernel<<<grid, 256, 0, stream>>>(x, out, total_rows);
}